// Round 7
// baseline (362.432 us; speedup 1.0000x reference)
//
#include <hip/hip_runtime.h>
#include <hip/hip_bf16.h>

#define N_NODES 50000
#define M_PAD   50048          // 391 * 128
#define N_EDGES 800000
#define NEG_SLOPE 0.2f

#define SCAN_BLK 512
#define SCAN_NB ((N_NODES + SCAN_BLK - 1) / SCAN_BLK)   // 98

typedef __attribute__((ext_vector_type(8))) short bf16x8;
typedef __attribute__((ext_vector_type(4))) float f32x4;

__device__ __forceinline__ unsigned short f2bf(float f) {
    unsigned u = __float_as_uint(f);
    u += 0x7FFFu + ((u >> 16) & 1u);          // RNE
    return (unsigned short)(u >> 16);
}
__device__ __forceinline__ float bf2f(unsigned short h) {
    return __uint_as_float(((unsigned)h) << 16);
}

// ---------------- weights transpose + deg zero (first dispatch) ----------------

__global__ __launch_bounds__(256) void k_trans(const float* __restrict__ W1, const float* __restrict__ W2,
                                               const float* __restrict__ resW2,
                                               unsigned short* __restrict__ W1T, unsigned short* __restrict__ W2T,
                                               int* __restrict__ deg) {
    int gtid = (blockIdx.y * 10 + blockIdx.x) * 256 + threadIdx.x;
    for (int i = gtid; i < N_NODES; i += 10 * 8 * 256) deg[i] = 0;

    __shared__ unsigned short tile[32][33];
    int bx = blockIdx.x;
    const float* in;
    unsigned short* out;
    int Nn, n0;
    if (bx < 8)      { in = W1;    out = W1T;            Nn = 256; n0 = bx * 32; }
    else if (bx == 8){ in = W2;    out = W2T;            Nn = 32;  n0 = 0; }
    else             { in = resW2; out = W2T + 32 * 256; Nn = 32;  n0 = 0; }
    int k0 = blockIdx.y * 32;
    int tx = threadIdx.x & 31, ty = threadIdx.x >> 5;  // 32 x 8
    #pragma unroll
    for (int r = 0; r < 4; ++r) {
        int k = k0 + ty + r * 8;
        tile[ty + r * 8][tx] = f2bf(in[(size_t)k * Nn + n0 + tx]);
    }
    __syncthreads();
    #pragma unroll
    for (int r = 0; r < 4; ++r) {
        int n = ty + r * 8;
        out[(size_t)(n0 + n) * 256 + k0 + tx] = tile[tx][n];
    }
}

// ---------------- CSR build ----------------

__global__ __launch_bounds__(256) void k_hist(const int* __restrict__ dst, int* __restrict__ deg) {
    int i = blockIdx.x * 256 + threadIdx.x;
    if (i < N_EDGES) atomicAdd(&deg[dst[i]], 1);
}

__global__ __launch_bounds__(SCAN_BLK) void k_scan1(const int* __restrict__ deg,
                                                    int* __restrict__ rowoff,
                                                    int* __restrict__ bsum) {
    __shared__ int s[SCAN_BLK];
    int i = blockIdx.x * SCAN_BLK + threadIdx.x;
    int v = (i < N_NODES) ? deg[i] : 0;
    s[threadIdx.x] = v;
    __syncthreads();
    for (int off = 1; off < SCAN_BLK; off <<= 1) {
        int t = (threadIdx.x >= off) ? s[threadIdx.x - off] : 0;
        __syncthreads();
        s[threadIdx.x] += t;
        __syncthreads();
    }
    if (i < N_NODES) rowoff[i] = s[threadIdx.x];
    if (threadIdx.x == SCAN_BLK - 1) bsum[blockIdx.x] = s[SCAN_BLK - 1];
}

__global__ __launch_bounds__(SCAN_BLK) void k_scan3(const int* __restrict__ deg,
                                                    int* __restrict__ rowoff,
                                                    int* __restrict__ wp,
                                                    const int* __restrict__ bsum) {
    __shared__ int red[8];
    int t = threadIdx.x;
    int part = 0;
    for (int i = t; i < (int)blockIdx.x; i += SCAN_BLK) part += bsum[i];
    #pragma unroll
    for (int m = 1; m <= 32; m <<= 1) part += __shfl_xor(part, m, 64);
    if ((t & 63) == 0) red[t >> 6] = part;
    __syncthreads();
    if (t == 0) {
        int o = 0;
        #pragma unroll
        for (int w = 0; w < 8; ++w) o += red[w];
        red[0] = o;
    }
    __syncthreads();
    int off = red[0];
    int i = blockIdx.x * SCAN_BLK + t;
    if (i < N_NODES) {
        int excl = rowoff[i] - deg[i] + off;
        rowoff[i] = excl;
        wp[i] = excl;
    }
    if (i == 0) rowoff[N_NODES] = N_EDGES;
}

__global__ __launch_bounds__(256) void k_scatter(const int* __restrict__ src, const int* __restrict__ dst,
                                                 int* __restrict__ wp, int* __restrict__ csr_src) {
    int i = blockIdx.x * 256 + threadIdx.x;
    if (i < N_EDGES) {
        int p = atomicAdd(&wp[dst[i]], 1);
        csr_src[p] = src[i];
    }
}

// ---------------- GEMM1 + fused elr1: LDS-free, barrier-free ----------------
// B panel (64 KB) is L2-resident (shared by all 391 blocks); A rows reused 2x via L1.
// Fragments loaded straight from global: no __shared__, no __syncthreads.

__global__ __launch_bounds__(256) void k_gemm1f(const float* __restrict__ x,
                                                const unsigned short* __restrict__ BT,
                                                const float* __restrict__ al1, const float* __restrict__ ar1,
                                                unsigned short* __restrict__ Cb,
                                                float* __restrict__ el1, float* __restrict__ er1) {
    const int t = threadIdx.x;
    const int bm0 = blockIdx.x * 128;
    const int bn0 = blockIdx.y * 128;
    const int wave = t >> 6, lane = t & 63;
    const int wm = (wave & 1) * 64, wn = (wave >> 1) * 64;
    const int lm = lane & 15, quad = lane >> 4;

    f32x4 acc[4][4];
    #pragma unroll
    for (int i = 0; i < 4; ++i)
        #pragma unroll
        for (int j = 0; j < 4; ++j)
            #pragma unroll
            for (int r = 0; r < 4; ++r) acc[i][j][r] = 0.f;

    const unsigned short* bp[4];
    const float* ap[4];
    bool aok[4];
    #pragma unroll
    for (int i = 0; i < 4; ++i) {
        bp[i] = BT + (size_t)(bn0 + wn + i * 16 + lm) * 256 + quad * 8;
        int arow = bm0 + wm + i * 16 + lm;
        aok[i] = arow < N_NODES;
        ap[i] = x + (size_t)arow * 256 + quad * 8;
    }

    #pragma unroll 2
    for (int k0 = 0; k0 < 256; k0 += 32) {
        bf16x8 bfr[4], af[4];
        #pragma unroll
        for (int i = 0; i < 4; ++i)
            bfr[i] = *(const bf16x8*)(bp[i] + k0);
        #pragma unroll
        for (int i = 0; i < 4; ++i) {
            float4 a0 = make_float4(0.f, 0.f, 0.f, 0.f), a1 = a0;
            if (aok[i]) {
                a0 = *(const float4*)(ap[i] + k0);
                a1 = *(const float4*)(ap[i] + k0 + 4);
            }
            union { bf16x8 v; unsigned short u[8]; } c;
            c.u[0] = f2bf(a0.x); c.u[1] = f2bf(a0.y); c.u[2] = f2bf(a0.z); c.u[3] = f2bf(a0.w);
            c.u[4] = f2bf(a1.x); c.u[5] = f2bf(a1.y); c.u[6] = f2bf(a1.z); c.u[7] = f2bf(a1.w);
            af[i] = c.v;
        }
        #pragma unroll
        for (int mi = 0; mi < 4; ++mi)
            #pragma unroll
            for (int ni = 0; ni < 4; ++ni)
                acc[mi][ni] = __builtin_amdgcn_mfma_f32_16x16x32_bf16(af[mi], bfr[ni], acc[mi][ni], 0, 0, 0);
    }

    // store feat1b (C/D layout: col=lane&15, row=quad*4+r)
    #pragma unroll
    for (int mi = 0; mi < 4; ++mi) {
        #pragma unroll
        for (int ni = 0; ni < 4; ++ni) {
            int col = bn0 + wn + ni * 16 + lm;
            #pragma unroll
            for (int r = 0; r < 4; ++r) {
                int row = bm0 + wm + mi * 16 + quad * 4 + r;
                if (row < N_NODES)
                    Cb[(size_t)row * 256 + col] = f2bf(acc[mi][ni][r]);
            }
        }
    }
    // fused elr1: wave's 64 cols = 2 heads
    float alv[4], arv[4];
    #pragma unroll
    for (int ni = 0; ni < 4; ++ni) {
        int colg = bn0 + wn + ni * 16 + lm;
        alv[ni] = al1[colg];
        arv[ni] = ar1[colg];
    }
    int head0 = (bn0 + wn) >> 5;
    #pragma unroll
    for (int g = 0; g < 2; ++g) {
        #pragma unroll
        for (int mi = 0; mi < 4; ++mi) {
            #pragma unroll
            for (int r = 0; r < 4; ++r) {
                float pel = acc[mi][2 * g][r] * alv[2 * g] + acc[mi][2 * g + 1][r] * alv[2 * g + 1];
                float per = acc[mi][2 * g][r] * arv[2 * g] + acc[mi][2 * g + 1][r] * arv[2 * g + 1];
                #pragma unroll
                for (int m = 1; m <= 8; m <<= 1) {
                    pel += __shfl_xor(pel, m, 64);
                    per += __shfl_xor(per, m, 64);
                }
                if (lm == 0) {
                    int row = bm0 + wm + mi * 16 + quad * 4 + r;
                    if (row < N_NODES) {
                        el1[row * 8 + head0 + g] = pel;
                        er1[row * 8 + head0 + g] = per;
                    }
                }
            }
        }
    }
}

// ---------------- L1 aggregation: one wave per dst node (8-edge batched unroll) ----------------

__global__ __launch_bounds__(256) void k_agg1(const unsigned short* __restrict__ feat1b,
                                              const float* __restrict__ el1, const float* __restrict__ er1,
                                              const float* __restrict__ x, const float* __restrict__ b1,
                                              const int* __restrict__ rowoff, const int* __restrict__ csr_src,
                                              unsigned short* __restrict__ y_b) {
    int v = (blockIdx.x * 256 + threadIdx.x) >> 6;
    int lane = threadIdx.x & 63;
    if (v >= N_NODES) return;
    int h = lane >> 3;
    float er = er1[v * 8 + h];
    int c0 = lane * 4;
    float ax = 0.f, ay = 0.f, az = 0.f, aw = 0.f, wsum = 0.f;
    int s = rowoff[v], e = rowoff[v + 1];
    int j = s;
    for (; j + 7 < e; j += 8) {
        int u[8];
        #pragma unroll
        for (int q = 0; q < 8; ++q) u[q] = csr_src[j + q];
        float tt[8];
        #pragma unroll
        for (int q = 0; q < 8; ++q) tt[q] = el1[u[q] * 8 + h] + er;
        ushort4 hv[8];
        #pragma unroll
        for (int q = 0; q < 8; ++q) hv[q] = *(const ushort4*)(feat1b + (size_t)u[q] * 256 + c0);
        #pragma unroll
        for (int q = 0; q < 8; ++q) {
            float tq = tt[q] > 0.f ? tt[q] : NEG_SLOPE * tt[q];
            float w = __expf(tq);
            wsum += w;
            ax += w * bf2f(hv[q].x);
            ay += w * bf2f(hv[q].y);
            az += w * bf2f(hv[q].z);
            aw += w * bf2f(hv[q].w);
        }
    }
    for (; j + 3 < e; j += 4) {
        int u[4];
        #pragma unroll
        for (int q = 0; q < 4; ++q) u[q] = csr_src[j + q];
        float tt[4];
        #pragma unroll
        for (int q = 0; q < 4; ++q) tt[q] = el1[u[q] * 8 + h] + er;
        ushort4 hv[4];
        #pragma unroll
        for (int q = 0; q < 4; ++q) hv[q] = *(const ushort4*)(feat1b + (size_t)u[q] * 256 + c0);
        #pragma unroll
        for (int q = 0; q < 4; ++q) {
            float tq = tt[q] > 0.f ? tt[q] : NEG_SLOPE * tt[q];
            float w = __expf(tq);
            wsum += w;
            ax += w * bf2f(hv[q].x);
            ay += w * bf2f(hv[q].y);
            az += w * bf2f(hv[q].z);
            aw += w * bf2f(hv[q].w);
        }
    }
    for (; j < e; ++j) {
        int u = csr_src[j];
        float t = el1[u * 8 + h] + er;
        ushort4 hh = *(const ushort4*)(feat1b + (size_t)u * 256 + c0);
        t = t > 0.f ? t : NEG_SLOPE * t;
        float w = __expf(t);
        wsum += w;
        ax += w * bf2f(hh.x);
        ay += w * bf2f(hh.y);
        az += w * bf2f(hh.z);
        aw += w * bf2f(hh.w);
    }
    float inv = (e > s) ? 1.f / wsum : 0.f;
    float4 r = *(const float4*)(x + (size_t)v * 256 + c0);
    float4 bb = *(const float4*)(b1 + c0);
    ushort4 o;
    o.x = f2bf(fmaxf(ax * inv + r.x + bb.x, 0.f));
    o.y = f2bf(fmaxf(ay * inv + r.y + bb.y, 0.f));
    o.z = f2bf(fmaxf(az * inv + r.z + bb.z, 0.f));
    o.w = f2bf(fmaxf(aw * inv + r.w + bb.w, 0.f));
    *(ushort4*)(y_b + (size_t)v * 256 + c0) = o;
}

// ---------------- GEMM2 + fused elr2: LDS-free, barrier-free ----------------
// A = y_b bf16 (M_PAD rows exist; padded rows garbage but outputs guarded).

__global__ __launch_bounds__(256) void k_gemm2f(const unsigned short* __restrict__ Ab,
                                                const unsigned short* __restrict__ BT,  // [64][256]
                                                const float* __restrict__ al2, const float* __restrict__ ar2,
                                                unsigned short* __restrict__ feat2b, float* __restrict__ res2,
                                                float* __restrict__ el2, float* __restrict__ er2) {
    const int t = threadIdx.x;
    const int bm0 = blockIdx.x * 128;
    const int wave = t >> 6, lane = t & 63;
    const int wm = (wave & 1) * 64, wn = (wave >> 1) * 32;
    const int lm = lane & 15, quad = lane >> 4;

    f32x4 acc[4][2];
    #pragma unroll
    for (int i = 0; i < 4; ++i)
        #pragma unroll
        for (int j = 0; j < 2; ++j)
            #pragma unroll
            for (int r = 0; r < 4; ++r) acc[i][j][r] = 0.f;

    const unsigned short* bp[2];
    const unsigned short* ap[4];
    #pragma unroll
    for (int i = 0; i < 2; ++i)
        bp[i] = BT + (size_t)(wn + i * 16 + lm) * 256 + quad * 8;
    #pragma unroll
    for (int i = 0; i < 4; ++i)
        ap[i] = Ab + (size_t)(bm0 + wm + i * 16 + lm) * 256 + quad * 8;

    #pragma unroll 2
    for (int k0 = 0; k0 < 256; k0 += 32) {
        bf16x8 af[4], bfr[2];
        #pragma unroll
        for (int i = 0; i < 2; ++i)
            bfr[i] = *(const bf16x8*)(bp[i] + k0);
        #pragma unroll
        for (int i = 0; i < 4; ++i)
            af[i] = *(const bf16x8*)(ap[i] + k0);
        #pragma unroll
        for (int mi = 0; mi < 4; ++mi)
            #pragma unroll
            for (int ni = 0; ni < 2; ++ni)
                acc[mi][ni] = __builtin_amdgcn_mfma_f32_16x16x32_bf16(af[mi], bfr[ni], acc[mi][ni], 0, 0, 0);
    }

    #pragma unroll
    for (int mi = 0; mi < 4; ++mi) {
        #pragma unroll
        for (int ni = 0; ni < 2; ++ni) {
            int col = wn + ni * 16 + lm;  // 0..63
            #pragma unroll
            for (int r = 0; r < 4; ++r) {
                int row = bm0 + wm + mi * 16 + quad * 4 + r;
                if (row < N_NODES) {
                    float val = acc[mi][ni][r];
                    if (col < 32) feat2b[(size_t)row * 32 + col] = f2bf(val);
                    else          res2[(size_t)row * 32 + col - 32] = val;
                }
            }
        }
    }
    if (wn == 0) {
        float alv[2], arv[2];
        #pragma unroll
        for (int ni = 0; ni < 2; ++ni) {
            alv[ni] = al2[ni * 16 + lm];
            arv[ni] = ar2[ni * 16 + lm];
        }
        #pragma unroll
        for (int mi = 0; mi < 4; ++mi) {
            #pragma unroll
            for (int r = 0; r < 4; ++r) {
                float pel = acc[mi][0][r] * alv[0] + acc[mi][1][r] * alv[1];
                float per = acc[mi][0][r] * arv[0] + acc[mi][1][r] * arv[1];
                #pragma unroll
                for (int m = 1; m <= 8; m <<= 1) {
                    pel += __shfl_xor(pel, m, 64);
                    per += __shfl_xor(per, m, 64);
                }
                if (lm == 0) {
                    int row = bm0 + wm + mi * 16 + quad * 4 + r;
                    if (row < N_NODES) {
                        el2[row] = pel;
                        er2[row] = per;
                    }
                }
            }
        }
    }
}

// ---------------- L2 aggregation: 32 lanes per dst node (4-edge batched unroll) ----------------

__global__ __launch_bounds__(256) void k_agg2(const unsigned short* __restrict__ feat2b,
                                              const float* __restrict__ el2, const float* __restrict__ er2,
                                              const float* __restrict__ res2, const float* __restrict__ b2,
                                              const int* __restrict__ rowoff, const int* __restrict__ csr_src,
                                              float* __restrict__ out) {
    int g = blockIdx.x * 256 + threadIdx.x;
    int v = g >> 5;
    int c = g & 31;
    if (v >= N_NODES) return;
    float er = er2[v];
    float acc = 0.f, wsum = 0.f;
    int s = rowoff[v], e = rowoff[v + 1];
    int j = s;
    for (; j + 3 < e; j += 4) {
        int u[4];
        #pragma unroll
        for (int q = 0; q < 4; ++q) u[q] = csr_src[j + q];
        float tt[4];
        #pragma unroll
        for (int q = 0; q < 4; ++q) tt[q] = el2[u[q]] + er;
        unsigned short fv[4];
        #pragma unroll
        for (int q = 0; q < 4; ++q) fv[q] = feat2b[(size_t)u[q] * 32 + c];
        #pragma unroll
        for (int q = 0; q < 4; ++q) {
            float tq = tt[q] > 0.f ? tt[q] : NEG_SLOPE * tt[q];
            float w = __expf(tq);
            wsum += w;
            acc += w * bf2f(fv[q]);
        }
    }
    for (; j < e; ++j) {
        int u = csr_src[j];
        float t = el2[u] + er;
        t = t > 0.f ? t : NEG_SLOPE * t;
        float w = __expf(t);
        wsum += w;
        acc += w * bf2f(feat2b[(size_t)u * 32 + c]);
    }
    float inv = (e > s) ? 1.f / wsum : 0.f;
    out[(size_t)v * 32 + c] = acc * inv + res2[(size_t)v * 32 + c] + b2[c];
}

// ---------------- launch ----------------

extern "C" void kernel_launch(void* const* d_in, const int* in_sizes, int n_in,
                              void* d_out, int out_size, void* d_ws, size_t ws_size,
                              hipStream_t stream) {
    const float* x     = (const float*)d_in[0];
    const int*   src   = (const int*)d_in[1];
    const int*   dst   = (const int*)d_in[2];
    const float* W1    = (const float*)d_in[3];
    const float* al1   = (const float*)d_in[4];
    const float* ar1   = (const float*)d_in[5];
    const float* b1    = (const float*)d_in[6];
    const float* W2    = (const float*)d_in[7];
    const float* al2   = (const float*)d_in[8];
    const float* ar2   = (const float*)d_in[9];
    const float* resW2 = (const float*)d_in[10];
    const float* b2    = (const float*)d_in[11];
    float* out = (float*)d_out;

    char* ws = (char*)d_ws;
    size_t off = 0;
    auto alloc = [&](size_t bytes) {
        void* p = ws + off;
        off += (bytes + 255) & ~(size_t)255;
        return p;
    };
    unsigned short* feat1b = (unsigned short*)alloc((size_t)N_NODES * 256 * 2);
    unsigned short* y_b    = (unsigned short*)alloc((size_t)M_PAD * 256 * 2);
    unsigned short* W1T    = (unsigned short*)alloc((size_t)256 * 256 * 2);
    unsigned short* W2T    = (unsigned short*)alloc((size_t)64 * 256 * 2);
    unsigned short* feat2b = (unsigned short*)alloc((size_t)N_NODES * 32 * 2);
    float* res2   = (float*)alloc((size_t)N_NODES * 32 * 4);
    float* el1    = (float*)alloc((size_t)N_NODES * 8 * 4);
    float* er1    = (float*)alloc((size_t)N_NODES * 8 * 4);
    float* el2    = (float*)alloc((size_t)N_NODES * 4);
    float* er2    = (float*)alloc((size_t)N_NODES * 4);
    int*   deg    = (int*)alloc((size_t)N_NODES * 4);
    int*   rowoff = (int*)alloc((size_t)(N_NODES + 1) * 4);
    int*   wp     = (int*)alloc((size_t)N_NODES * 4);
    int*   bsum   = (int*)alloc((size_t)SCAN_NB * 4);
    int*   csr    = (int*)alloc((size_t)N_EDGES * 4);
    (void)ws_size;

    // weights transpose + deg zeroing
    k_trans<<<dim3(10, 8), 256, 0, stream>>>(W1, W2, resW2, W1T, W2T, deg);

    // CSR build (rebuilt every call)
    k_hist<<<(N_EDGES + 255) / 256, 256, 0, stream>>>(dst, deg);
    k_scan1<<<SCAN_NB, SCAN_BLK, 0, stream>>>(deg, rowoff, bsum);
    k_scan3<<<SCAN_NB, SCAN_BLK, 0, stream>>>(deg, rowoff, wp, bsum);
    k_scatter<<<(N_EDGES + 255) / 256, 256, 0, stream>>>(src, dst, wp, csr);

    // Layer 1
    k_gemm1f<<<dim3(M_PAD / 128, 2), 256, 0, stream>>>(x, W1T, al1, ar1, feat1b, el1, er1);
    k_agg1<<<(N_NODES * 64) / 256, 256, 0, stream>>>(feat1b, el1, er1, x, b1, rowoff, csr, y_b);

    // Layer 2
    k_gemm2f<<<M_PAD / 128, 256, 0, stream>>>(y_b, W2T, al2, ar2, feat2b, res2, el2, er2);
    k_agg2<<<(N_NODES * 32) / 256, 256, 0, stream>>>(feat2b, el2, er2, res2, b2, rowoff, csr, out);
}

// Round 8
// 349.184 us; speedup vs baseline: 1.0379x; 1.0379x over previous
//
#include <hip/hip_runtime.h>
#include <hip/hip_bf16.h>

#define N_NODES 50000
#define M_PAD   50048          // 391 * 128
#define N_EDGES 800000
#define NEG_SLOPE 0.2f

#define SCAN_BLK 512
#define SCAN_NB ((N_NODES + SCAN_BLK - 1) / SCAN_BLK)   // 98

typedef __attribute__((ext_vector_type(8))) short bf16x8;
typedef __attribute__((ext_vector_type(4))) float f32x4;

__device__ __forceinline__ unsigned short f2bf(float f) {
    unsigned u = __float_as_uint(f);
    u += 0x7FFFu + ((u >> 16) & 1u);          // RNE
    return (unsigned short)(u >> 16);
}
__device__ __forceinline__ float bf2f(unsigned short h) {
    return __uint_as_float(((unsigned)h) << 16);
}

// ---------------- weights transpose + deg zero (first dispatch) ----------------

__global__ __launch_bounds__(256) void k_trans(const float* __restrict__ W1, const float* __restrict__ W2,
                                               const float* __restrict__ resW2,
                                               unsigned short* __restrict__ W1T, unsigned short* __restrict__ W2T,
                                               int* __restrict__ deg) {
    int gtid = (blockIdx.y * 10 + blockIdx.x) * 256 + threadIdx.x;
    for (int i = gtid; i < N_NODES; i += 10 * 8 * 256) deg[i] = 0;

    __shared__ unsigned short tile[32][33];
    int bx = blockIdx.x;
    const float* in;
    unsigned short* out;
    int Nn, n0;
    if (bx < 8)      { in = W1;    out = W1T;            Nn = 256; n0 = bx * 32; }
    else if (bx == 8){ in = W2;    out = W2T;            Nn = 32;  n0 = 0; }
    else             { in = resW2; out = W2T + 32 * 256; Nn = 32;  n0 = 0; }
    int k0 = blockIdx.y * 32;
    int tx = threadIdx.x & 31, ty = threadIdx.x >> 5;  // 32 x 8
    #pragma unroll
    for (int r = 0; r < 4; ++r) {
        int k = k0 + ty + r * 8;
        tile[ty + r * 8][tx] = f2bf(in[(size_t)k * Nn + n0 + tx]);
    }
    __syncthreads();
    #pragma unroll
    for (int r = 0; r < 4; ++r) {
        int n = ty + r * 8;
        out[(size_t)(n0 + n) * 256 + k0 + tx] = tile[tx][n];
    }
}

// ---------------- CSR hist + fused xb cast ----------------
// 3125 blocks: 800K threads do one atomic each + grid-stride cast of x -> bf16 (pad rows zeroed).

__global__ __launch_bounds__(256) void k_hist(const int* __restrict__ dst, int* __restrict__ deg,
                                              const float* __restrict__ x, unsigned short* __restrict__ xb) {
    int i = blockIdx.x * 256 + threadIdx.x;
    if (i < N_EDGES) atomicAdd(&deg[dst[i]], 1);
    const size_t NCHUNK = (size_t)M_PAD * 256 / 8;
    for (size_t c = (size_t)blockIdx.x * 256 + threadIdx.x; c < NCHUNK; c += (size_t)gridDim.x * 256) {
        size_t base = c * 8;
        float4 a = make_float4(0.f, 0.f, 0.f, 0.f), b = a;
        if (base < (size_t)N_NODES * 256) {
            a = *(const float4*)(x + base);
            b = *(const float4*)(x + base + 4);
        }
        ushort4 h0, h1;
        h0.x = f2bf(a.x); h0.y = f2bf(a.y); h0.z = f2bf(a.z); h0.w = f2bf(a.w);
        h1.x = f2bf(b.x); h1.y = f2bf(b.y); h1.z = f2bf(b.z); h1.w = f2bf(b.w);
        *(ushort4*)(xb + base) = h0;
        *(ushort4*)(xb + base + 4) = h1;
    }
}

__global__ __launch_bounds__(SCAN_BLK) void k_scan1(const int* __restrict__ deg,
                                                    int* __restrict__ rowoff,
                                                    int* __restrict__ bsum) {
    __shared__ int s[SCAN_BLK];
    int i = blockIdx.x * SCAN_BLK + threadIdx.x;
    int v = (i < N_NODES) ? deg[i] : 0;
    s[threadIdx.x] = v;
    __syncthreads();
    for (int off = 1; off < SCAN_BLK; off <<= 1) {
        int t = (threadIdx.x >= off) ? s[threadIdx.x - off] : 0;
        __syncthreads();
        s[threadIdx.x] += t;
        __syncthreads();
    }
    if (i < N_NODES) rowoff[i] = s[threadIdx.x];
    if (threadIdx.x == SCAN_BLK - 1) bsum[blockIdx.x] = s[SCAN_BLK - 1];
}

__global__ __launch_bounds__(SCAN_BLK) void k_scan3(const int* __restrict__ deg,
                                                    int* __restrict__ rowoff,
                                                    int* __restrict__ wp,
                                                    const int* __restrict__ bsum) {
    __shared__ int red[8];
    int t = threadIdx.x;
    int part = 0;
    for (int i = t; i < (int)blockIdx.x; i += SCAN_BLK) part += bsum[i];
    #pragma unroll
    for (int m = 1; m <= 32; m <<= 1) part += __shfl_xor(part, m, 64);
    if ((t & 63) == 0) red[t >> 6] = part;
    __syncthreads();
    if (t == 0) {
        int o = 0;
        #pragma unroll
        for (int w = 0; w < 8; ++w) o += red[w];
        red[0] = o;
    }
    __syncthreads();
    int off = red[0];
    int i = blockIdx.x * SCAN_BLK + t;
    if (i < N_NODES) {
        int excl = rowoff[i] - deg[i] + off;
        rowoff[i] = excl;
        wp[i] = excl;
    }
    if (i == 0) rowoff[N_NODES] = N_EDGES;
}

__global__ __launch_bounds__(256) void k_scatter(const int* __restrict__ src, const int* __restrict__ dst,
                                                 int* __restrict__ wp, int* __restrict__ csr_src) {
    int i = blockIdx.x * 256 + threadIdx.x;
    if (i < N_EDGES) {
        int p = atomicAdd(&wp[dst[i]], 1);
        csr_src[p] = src[i];
    }
}

// ---------------- GEMM1 + fused elr1: LDS-free, barrier-free, guard-free ----------------
// A = xb bf16 (pad rows zero). B panel 64KB L2-resident. Full K unroll.

__global__ __launch_bounds__(256) void k_gemm1f(const unsigned short* __restrict__ xb,
                                                const unsigned short* __restrict__ BT,
                                                const float* __restrict__ al1, const float* __restrict__ ar1,
                                                unsigned short* __restrict__ Cb,
                                                float* __restrict__ el1, float* __restrict__ er1) {
    const int t = threadIdx.x;
    const int bm0 = blockIdx.x * 128;
    const int bn0 = blockIdx.y * 128;
    const int wave = t >> 6, lane = t & 63;
    const int wm = (wave & 1) * 64, wn = (wave >> 1) * 64;
    const int lm = lane & 15, quad = lane >> 4;

    f32x4 acc[4][4];
    #pragma unroll
    for (int i = 0; i < 4; ++i)
        #pragma unroll
        for (int j = 0; j < 4; ++j)
            #pragma unroll
            for (int r = 0; r < 4; ++r) acc[i][j][r] = 0.f;

    const unsigned short* bp[4];
    const unsigned short* ap[4];
    #pragma unroll
    for (int i = 0; i < 4; ++i) {
        bp[i] = BT + (size_t)(bn0 + wn + i * 16 + lm) * 256 + quad * 8;
        ap[i] = xb + (size_t)(bm0 + wm + i * 16 + lm) * 256 + quad * 8;
    }

    #pragma unroll
    for (int k0 = 0; k0 < 256; k0 += 32) {
        bf16x8 bfr[4], af[4];
        #pragma unroll
        for (int i = 0; i < 4; ++i)
            bfr[i] = *(const bf16x8*)(bp[i] + k0);
        #pragma unroll
        for (int i = 0; i < 4; ++i)
            af[i] = *(const bf16x8*)(ap[i] + k0);
        #pragma unroll
        for (int mi = 0; mi < 4; ++mi)
            #pragma unroll
            for (int ni = 0; ni < 4; ++ni)
                acc[mi][ni] = __builtin_amdgcn_mfma_f32_16x16x32_bf16(af[mi], bfr[ni], acc[mi][ni], 0, 0, 0);
    }

    // store feat1b (C/D layout: col=lane&15, row=quad*4+r); M_PAD-sized, no guards
    #pragma unroll
    for (int mi = 0; mi < 4; ++mi) {
        #pragma unroll
        for (int ni = 0; ni < 4; ++ni) {
            int col = bn0 + wn + ni * 16 + lm;
            #pragma unroll
            for (int r = 0; r < 4; ++r) {
                int row = bm0 + wm + mi * 16 + quad * 4 + r;
                Cb[(size_t)row * 256 + col] = f2bf(acc[mi][ni][r]);
            }
        }
    }
    // fused elr1: wave's 64 cols = 2 heads
    float alv[4], arv[4];
    #pragma unroll
    for (int ni = 0; ni < 4; ++ni) {
        int colg = bn0 + wn + ni * 16 + lm;
        alv[ni] = al1[colg];
        arv[ni] = ar1[colg];
    }
    int head0 = (bn0 + wn) >> 5;
    #pragma unroll
    for (int g = 0; g < 2; ++g) {
        #pragma unroll
        for (int mi = 0; mi < 4; ++mi) {
            #pragma unroll
            for (int r = 0; r < 4; ++r) {
                float pel = acc[mi][2 * g][r] * alv[2 * g] + acc[mi][2 * g + 1][r] * alv[2 * g + 1];
                float per = acc[mi][2 * g][r] * arv[2 * g] + acc[mi][2 * g + 1][r] * arv[2 * g + 1];
                #pragma unroll
                for (int m = 1; m <= 8; m <<= 1) {
                    pel += __shfl_xor(pel, m, 64);
                    per += __shfl_xor(per, m, 64);
                }
                if (lm == 0) {
                    int row = bm0 + wm + mi * 16 + quad * 4 + r;
                    el1[row * 8 + head0 + g] = pel;
                    er1[row * 8 + head0 + g] = per;
                }
            }
        }
    }
}

// ---------------- L1 aggregation: one wave per dst node (8-edge batched unroll) ----------------
// Grid covers M_PAD; pad rows write zeros (so gemm2f needs no guards).

__global__ __launch_bounds__(256) void k_agg1(const unsigned short* __restrict__ feat1b,
                                              const float* __restrict__ el1, const float* __restrict__ er1,
                                              const unsigned short* __restrict__ xb, const float* __restrict__ b1,
                                              const int* __restrict__ rowoff, const int* __restrict__ csr_src,
                                              unsigned short* __restrict__ y_b) {
    int v = (blockIdx.x * 256 + threadIdx.x) >> 6;
    int lane = threadIdx.x & 63;
    if (v >= M_PAD) return;
    int c0 = lane * 4;
    if (v >= N_NODES) {
        ushort4 z = {0, 0, 0, 0};
        *(ushort4*)(y_b + (size_t)v * 256 + c0) = z;
        return;
    }
    int h = lane >> 3;
    float er = er1[v * 8 + h];
    float ax = 0.f, ay = 0.f, az = 0.f, aw = 0.f, wsum = 0.f;
    int s = rowoff[v], e = rowoff[v + 1];
    int j = s;
    for (; j + 7 < e; j += 8) {
        int u[8];
        #pragma unroll
        for (int q = 0; q < 8; ++q) u[q] = csr_src[j + q];
        float tt[8];
        #pragma unroll
        for (int q = 0; q < 8; ++q) tt[q] = el1[u[q] * 8 + h] + er;
        ushort4 hv[8];
        #pragma unroll
        for (int q = 0; q < 8; ++q) hv[q] = *(const ushort4*)(feat1b + (size_t)u[q] * 256 + c0);
        #pragma unroll
        for (int q = 0; q < 8; ++q) {
            float tq = tt[q] > 0.f ? tt[q] : NEG_SLOPE * tt[q];
            float w = __expf(tq);
            wsum += w;
            ax += w * bf2f(hv[q].x);
            ay += w * bf2f(hv[q].y);
            az += w * bf2f(hv[q].z);
            aw += w * bf2f(hv[q].w);
        }
    }
    for (; j + 3 < e; j += 4) {
        int u[4];
        #pragma unroll
        for (int q = 0; q < 4; ++q) u[q] = csr_src[j + q];
        float tt[4];
        #pragma unroll
        for (int q = 0; q < 4; ++q) tt[q] = el1[u[q] * 8 + h] + er;
        ushort4 hv[4];
        #pragma unroll
        for (int q = 0; q < 4; ++q) hv[q] = *(const ushort4*)(feat1b + (size_t)u[q] * 256 + c0);
        #pragma unroll
        for (int q = 0; q < 4; ++q) {
            float tq = tt[q] > 0.f ? tt[q] : NEG_SLOPE * tt[q];
            float w = __expf(tq);
            wsum += w;
            ax += w * bf2f(hv[q].x);
            ay += w * bf2f(hv[q].y);
            az += w * bf2f(hv[q].z);
            aw += w * bf2f(hv[q].w);
        }
    }
    for (; j < e; ++j) {
        int u = csr_src[j];
        float t = el1[u * 8 + h] + er;
        ushort4 hh = *(const ushort4*)(feat1b + (size_t)u * 256 + c0);
        t = t > 0.f ? t : NEG_SLOPE * t;
        float w = __expf(t);
        wsum += w;
        ax += w * bf2f(hh.x);
        ay += w * bf2f(hh.y);
        az += w * bf2f(hh.z);
        aw += w * bf2f(hh.w);
    }
    float inv = (e > s) ? 1.f / wsum : 0.f;
    ushort4 rh = *(const ushort4*)(xb + (size_t)v * 256 + c0);
    float4 bb = *(const float4*)(b1 + c0);
    ushort4 o;
    o.x = f2bf(fmaxf(ax * inv + bf2f(rh.x) + bb.x, 0.f));
    o.y = f2bf(fmaxf(ay * inv + bf2f(rh.y) + bb.y, 0.f));
    o.z = f2bf(fmaxf(az * inv + bf2f(rh.z) + bb.z, 0.f));
    o.w = f2bf(fmaxf(aw * inv + bf2f(rh.w) + bb.w, 0.f));
    *(ushort4*)(y_b + (size_t)v * 256 + c0) = o;
}

// ---------------- GEMM2 + fused elr2: LDS-free, barrier-free, guard-free ----------------

__global__ __launch_bounds__(256) void k_gemm2f(const unsigned short* __restrict__ Ab,
                                                const unsigned short* __restrict__ BT,  // [64][256]
                                                const float* __restrict__ al2, const float* __restrict__ ar2,
                                                unsigned short* __restrict__ feat2b, float* __restrict__ res2,
                                                float* __restrict__ el2, float* __restrict__ er2) {
    const int t = threadIdx.x;
    const int bm0 = blockIdx.x * 128;
    const int wave = t >> 6, lane = t & 63;
    const int wm = (wave & 1) * 64, wn = (wave >> 1) * 32;
    const int lm = lane & 15, quad = lane >> 4;

    f32x4 acc[4][2];
    #pragma unroll
    for (int i = 0; i < 4; ++i)
        #pragma unroll
        for (int j = 0; j < 2; ++j)
            #pragma unroll
            for (int r = 0; r < 4; ++r) acc[i][j][r] = 0.f;

    const unsigned short* bp[2];
    const unsigned short* ap[4];
    #pragma unroll
    for (int i = 0; i < 2; ++i)
        bp[i] = BT + (size_t)(wn + i * 16 + lm) * 256 + quad * 8;
    #pragma unroll
    for (int i = 0; i < 4; ++i)
        ap[i] = Ab + (size_t)(bm0 + wm + i * 16 + lm) * 256 + quad * 8;

    #pragma unroll
    for (int k0 = 0; k0 < 256; k0 += 32) {
        bf16x8 af[4], bfr[2];
        #pragma unroll
        for (int i = 0; i < 2; ++i)
            bfr[i] = *(const bf16x8*)(bp[i] + k0);
        #pragma unroll
        for (int i = 0; i < 4; ++i)
            af[i] = *(const bf16x8*)(ap[i] + k0);
        #pragma unroll
        for (int mi = 0; mi < 4; ++mi)
            #pragma unroll
            for (int ni = 0; ni < 2; ++ni)
                acc[mi][ni] = __builtin_amdgcn_mfma_f32_16x16x32_bf16(af[mi], bfr[ni], acc[mi][ni], 0, 0, 0);
    }

    #pragma unroll
    for (int mi = 0; mi < 4; ++mi) {
        #pragma unroll
        for (int ni = 0; ni < 2; ++ni) {
            int col = wn + ni * 16 + lm;  // 0..63
            #pragma unroll
            for (int r = 0; r < 4; ++r) {
                int row = bm0 + wm + mi * 16 + quad * 4 + r;
                float val = acc[mi][ni][r];
                if (col < 32) feat2b[(size_t)row * 32 + col] = f2bf(val);
                else          res2[(size_t)row * 32 + col - 32] = val;
            }
        }
    }
    if (wn == 0) {
        float alv[2], arv[2];
        #pragma unroll
        for (int ni = 0; ni < 2; ++ni) {
            alv[ni] = al2[ni * 16 + lm];
            arv[ni] = ar2[ni * 16 + lm];
        }
        #pragma unroll
        for (int mi = 0; mi < 4; ++mi) {
            #pragma unroll
            for (int r = 0; r < 4; ++r) {
                float pel = acc[mi][0][r] * alv[0] + acc[mi][1][r] * alv[1];
                float per = acc[mi][0][r] * arv[0] + acc[mi][1][r] * arv[1];
                #pragma unroll
                for (int m = 1; m <= 8; m <<= 1) {
                    pel += __shfl_xor(pel, m, 64);
                    per += __shfl_xor(per, m, 64);
                }
                if (lm == 0) {
                    int row = bm0 + wm + mi * 16 + quad * 4 + r;
                    el2[row] = pel;
                    er2[row] = per;
                }
            }
        }
    }
}

// ---------------- L2 aggregation: 32 lanes per dst node (4-edge batched unroll) ----------------

__global__ __launch_bounds__(256) void k_agg2(const unsigned short* __restrict__ feat2b,
                                              const float* __restrict__ el2, const float* __restrict__ er2,
                                              const float* __restrict__ res2, const float* __restrict__ b2,
                                              const int* __restrict__ rowoff, const int* __restrict__ csr_src,
                                              float* __restrict__ out) {
    int g = blockIdx.x * 256 + threadIdx.x;
    int v = g >> 5;
    int c = g & 31;
    if (v >= N_NODES) return;
    float er = er2[v];
    float acc = 0.f, wsum = 0.f;
    int s = rowoff[v], e = rowoff[v + 1];
    int j = s;
    for (; j + 3 < e; j += 4) {
        int u[4];
        #pragma unroll
        for (int q = 0; q < 4; ++q) u[q] = csr_src[j + q];
        float tt[4];
        #pragma unroll
        for (int q = 0; q < 4; ++q) tt[q] = el2[u[q]] + er;
        unsigned short fv[4];
        #pragma unroll
        for (int q = 0; q < 4; ++q) fv[q] = feat2b[(size_t)u[q] * 32 + c];
        #pragma unroll
        for (int q = 0; q < 4; ++q) {
            float tq = tt[q] > 0.f ? tt[q] : NEG_SLOPE * tt[q];
            float w = __expf(tq);
            wsum += w;
            acc += w * bf2f(fv[q]);
        }
    }
    for (; j < e; ++j) {
        int u = csr_src[j];
        float t = el2[u] + er;
        t = t > 0.f ? t : NEG_SLOPE * t;
        float w = __expf(t);
        wsum += w;
        acc += w * bf2f(feat2b[(size_t)u * 32 + c]);
    }
    float inv = (e > s) ? 1.f / wsum : 0.f;
    out[(size_t)v * 32 + c] = acc * inv + res2[(size_t)v * 32 + c] + b2[c];
}

// ---------------- launch ----------------

extern "C" void kernel_launch(void* const* d_in, const int* in_sizes, int n_in,
                              void* d_out, int out_size, void* d_ws, size_t ws_size,
                              hipStream_t stream) {
    const float* x     = (const float*)d_in[0];
    const int*   src   = (const int*)d_in[1];
    const int*   dst   = (const int*)d_in[2];
    const float* W1    = (const float*)d_in[3];
    const float* al1   = (const float*)d_in[4];
    const float* ar1   = (const float*)d_in[5];
    const float* b1    = (const float*)d_in[6];
    const float* W2    = (const float*)d_in[7];
    const float* al2   = (const float*)d_in[8];
    const float* ar2   = (const float*)d_in[9];
    const float* resW2 = (const float*)d_in[10];
    const float* b2    = (const float*)d_in[11];
    float* out = (float*)d_out;

    char* ws = (char*)d_ws;
    size_t off = 0;
    auto alloc = [&](size_t bytes) {
        void* p = ws + off;
        off += (bytes + 255) & ~(size_t)255;
        return p;
    };
    unsigned short* xb     = (unsigned short*)alloc((size_t)M_PAD * 256 * 2);
    unsigned short* feat1b = (unsigned short*)alloc((size_t)M_PAD * 256 * 2);
    unsigned short* y_b    = (unsigned short*)alloc((size_t)M_PAD * 256 * 2);
    unsigned short* W1T    = (unsigned short*)alloc((size_t)256 * 256 * 2);
    unsigned short* W2T    = (unsigned short*)alloc((size_t)64 * 256 * 2);
    unsigned short* feat2b = (unsigned short*)alloc((size_t)M_PAD * 32 * 2);
    float* res2   = (float*)alloc((size_t)M_PAD * 32 * 4);
    float* el1    = (float*)alloc((size_t)M_PAD * 8 * 4);
    float* er1    = (float*)alloc((size_t)M_PAD * 8 * 4);
    float* el2    = (float*)alloc((size_t)M_PAD * 4);
    float* er2    = (float*)alloc((size_t)M_PAD * 4);
    int*   deg    = (int*)alloc((size_t)N_NODES * 4);
    int*   rowoff = (int*)alloc((size_t)(N_NODES + 1) * 4);
    int*   wp     = (int*)alloc((size_t)N_NODES * 4);
    int*   bsum   = (int*)alloc((size_t)SCAN_NB * 4);
    int*   csr    = (int*)alloc((size_t)N_EDGES * 4);
    (void)ws_size;

    // weights transpose + deg zeroing
    k_trans<<<dim3(10, 8), 256, 0, stream>>>(W1, W2, resW2, W1T, W2T, deg);

    // CSR build + fused xb cast
    k_hist<<<(N_EDGES + 255) / 256, 256, 0, stream>>>(dst, deg, x, xb);
    k_scan1<<<SCAN_NB, SCAN_BLK, 0, stream>>>(deg, rowoff, bsum);
    k_scan3<<<SCAN_NB, SCAN_BLK, 0, stream>>>(deg, rowoff, wp, bsum);
    k_scatter<<<(N_EDGES + 255) / 256, 256, 0, stream>>>(src, dst, wp, csr);

    // Layer 1
    k_gemm1f<<<dim3(M_PAD / 128, 2), 256, 0, stream>>>(xb, W1T, al1, ar1, feat1b, el1, er1);
    k_agg1<<<(M_PAD * 64) / 256, 256, 0, stream>>>(feat1b, el1, er1, xb, b1, rowoff, csr, y_b);

    // Layer 2
    k_gemm2f<<<M_PAD / 128, 256, 0, stream>>>(y_b, W2T, al2, ar2, feat2b, res2, el2, er2);
    k_agg2<<<(N_NODES * 32) / 256, 256, 0, stream>>>(feat2b, el2, er2, res2, b2, rowoff, csr, out);
}

// Round 9
// 318.958 us; speedup vs baseline: 1.1363x; 1.0948x over previous
//
#include <hip/hip_runtime.h>
#include <hip/hip_bf16.h>
#include <hip/hip_fp8.h>

#define N_NODES 50000
#define M_PAD   50048          // 391 * 128
#define N_EDGES 800000
#define NEG_SLOPE 0.2f

#define SCAN_BLK 256
#define SCAN_NB ((N_NODES + SCAN_BLK - 1) / SCAN_BLK)   // 196
#define GEMM1_BLOCKS 782                                 // 391 * 2

typedef __attribute__((ext_vector_type(8))) short bf16x8;
typedef __attribute__((ext_vector_type(4))) float f32x4;

__device__ __forceinline__ unsigned short f2bf(float f) {
    unsigned u = __float_as_uint(f);
    u += 0x7FFFu + ((u >> 16) & 1u);          // RNE
    return (unsigned short)(u >> 16);
}
__device__ __forceinline__ float bf2f(unsigned short h) {
    return __uint_as_float(((unsigned)h) << 16);
}
__device__ __forceinline__ unsigned char f2fp8(float f) {
    __hip_fp8_e4m3 t(f);                      // OCP e4m3, HW cvt on gfx950
    return (unsigned char)t.__x;
}
__device__ __forceinline__ float fp82f(unsigned char b) {
    __hip_fp8_e4m3 t;
    t.__x = (__hip_fp8_storage_t)b;
    return (float)t;
}

// ---------------- weights transpose + deg zero (first dispatch) ----------------

__global__ __launch_bounds__(256) void k_trans(const float* __restrict__ W1, const float* __restrict__ W2,
                                               const float* __restrict__ resW2,
                                               unsigned short* __restrict__ W1T, unsigned short* __restrict__ W2T,
                                               int* __restrict__ deg) {
    int gtid = (blockIdx.y * 10 + blockIdx.x) * 256 + threadIdx.x;
    for (int i = gtid; i < N_NODES; i += 10 * 8 * 256) deg[i] = 0;

    __shared__ unsigned short tile[32][33];
    int bx = blockIdx.x;
    const float* in;
    unsigned short* out;
    int Nn, n0;
    if (bx < 8)      { in = W1;    out = W1T;            Nn = 256; n0 = bx * 32; }
    else if (bx == 8){ in = W2;    out = W2T;            Nn = 32;  n0 = 0; }
    else             { in = resW2; out = W2T + 32 * 256; Nn = 32;  n0 = 0; }
    int k0 = blockIdx.y * 32;
    int tx = threadIdx.x & 31, ty = threadIdx.x >> 5;  // 32 x 8
    #pragma unroll
    for (int r = 0; r < 4; ++r) {
        int k = k0 + ty + r * 8;
        tile[ty + r * 8][tx] = f2bf(in[(size_t)k * Nn + n0 + tx]);
    }
    __syncthreads();
    #pragma unroll
    for (int r = 0; r < 4; ++r) {
        int n = ty + r * 8;
        out[(size_t)(n0 + n) * 256 + k0 + tx] = tile[tx][n];
    }
}

// ---------------- CSR hist + fused xb cast ----------------

__global__ __launch_bounds__(256) void k_hist(const int* __restrict__ dst, int* __restrict__ deg,
                                              const float* __restrict__ x, unsigned short* __restrict__ xb) {
    int i = blockIdx.x * 256 + threadIdx.x;
    if (i < N_EDGES) atomicAdd(&deg[dst[i]], 1);
    const size_t NCHUNK = (size_t)M_PAD * 256 / 8;
    for (size_t c = (size_t)blockIdx.x * 256 + threadIdx.x; c < NCHUNK; c += (size_t)gridDim.x * 256) {
        size_t base = c * 8;
        float4 a = make_float4(0.f, 0.f, 0.f, 0.f), b = a;
        if (base < (size_t)N_NODES * 256) {
            a = *(const float4*)(x + base);
            b = *(const float4*)(x + base + 4);
        }
        ushort4 h0, h1;
        h0.x = f2bf(a.x); h0.y = f2bf(a.y); h0.z = f2bf(a.z); h0.w = f2bf(a.w);
        h1.x = f2bf(b.x); h1.y = f2bf(b.y); h1.z = f2bf(b.z); h1.w = f2bf(b.w);
        *(ushort4*)(xb + base) = h0;
        *(ushort4*)(xb + base + 4) = h1;
    }
}

// ---------------- scan3: block-offset reduction + exclusive fixup ----------------

__global__ __launch_bounds__(SCAN_BLK) void k_scan3(const int* __restrict__ deg,
                                                    int* __restrict__ rowoff,
                                                    int* __restrict__ wp,
                                                    const int* __restrict__ bsum) {
    __shared__ int red[4];
    int t = threadIdx.x;
    int part = 0;
    for (int i = t; i < (int)blockIdx.x; i += SCAN_BLK) part += bsum[i];
    #pragma unroll
    for (int m = 1; m <= 32; m <<= 1) part += __shfl_xor(part, m, 64);
    if ((t & 63) == 0) red[t >> 6] = part;
    __syncthreads();
    if (t == 0) red[0] = red[0] + red[1] + red[2] + red[3];
    __syncthreads();
    int off = red[0];
    int i = blockIdx.x * SCAN_BLK + t;
    if (i < N_NODES) {
        int excl = rowoff[i] - deg[i] + off;
        rowoff[i] = excl;
        wp[i] = excl;
    }
    if (i == 0) rowoff[N_NODES] = N_EDGES;
}

__global__ __launch_bounds__(256) void k_scatter(const int* __restrict__ src, const int* __restrict__ dst,
                                                 int* __restrict__ wp, int* __restrict__ csr_src) {
    int i = blockIdx.x * 256 + threadIdx.x;
    if (i < N_EDGES) {
        int p = atomicAdd(&wp[dst[i]], 1);
        csr_src[p] = src[i];
    }
}

// ---------------- GEMM1 (fp8 out) + fused elr1 + co-scheduled scan1 ----------------
// Blocks 0..781: LDS-free MFMA GEMM. Blocks 782..977: scan1 (independent: reads deg only).

__global__ __launch_bounds__(256) void k_gemm1s(const unsigned short* __restrict__ xb,
                                                const unsigned short* __restrict__ BT,
                                                const float* __restrict__ al1, const float* __restrict__ ar1,
                                                unsigned char* __restrict__ Cb8,
                                                float* __restrict__ el1, float* __restrict__ er1,
                                                const int* __restrict__ deg, int* __restrict__ rowoff,
                                                int* __restrict__ bsum) {
    __shared__ int s[SCAN_BLK];
    if (blockIdx.x >= GEMM1_BLOCKS) {
        // ---- scan1 role ----
        int b = blockIdx.x - GEMM1_BLOCKS;
        int i = b * SCAN_BLK + threadIdx.x;
        int v = (i < N_NODES) ? deg[i] : 0;
        s[threadIdx.x] = v;
        __syncthreads();
        for (int off = 1; off < SCAN_BLK; off <<= 1) {
            int t2 = (threadIdx.x >= off) ? s[threadIdx.x - off] : 0;
            __syncthreads();
            s[threadIdx.x] += t2;
            __syncthreads();
        }
        if (i < N_NODES) rowoff[i] = s[threadIdx.x];
        if (threadIdx.x == SCAN_BLK - 1) bsum[b] = s[SCAN_BLK - 1];
        return;
    }
    // ---- GEMM role ----
    const int t = threadIdx.x;
    const int g = blockIdx.x;
    const int bm0 = (g % 391) * 128;
    const int bn0 = (g / 391) * 128;
    const int wave = t >> 6, lane = t & 63;
    const int wm = (wave & 1) * 64, wn = (wave >> 1) * 64;
    const int lm = lane & 15, quad = lane >> 4;

    f32x4 acc[4][4];
    #pragma unroll
    for (int i = 0; i < 4; ++i)
        #pragma unroll
        for (int j = 0; j < 4; ++j)
            #pragma unroll
            for (int r = 0; r < 4; ++r) acc[i][j][r] = 0.f;

    const unsigned short* bp[4];
    const unsigned short* ap[4];
    #pragma unroll
    for (int i = 0; i < 4; ++i) {
        bp[i] = BT + (size_t)(bn0 + wn + i * 16 + lm) * 256 + quad * 8;
        ap[i] = xb + (size_t)(bm0 + wm + i * 16 + lm) * 256 + quad * 8;
    }

    #pragma unroll
    for (int k0 = 0; k0 < 256; k0 += 32) {
        bf16x8 bfr[4], af[4];
        #pragma unroll
        for (int i = 0; i < 4; ++i)
            bfr[i] = *(const bf16x8*)(bp[i] + k0);
        #pragma unroll
        for (int i = 0; i < 4; ++i)
            af[i] = *(const bf16x8*)(ap[i] + k0);
        #pragma unroll
        for (int mi = 0; mi < 4; ++mi)
            #pragma unroll
            for (int ni = 0; ni < 4; ++ni)
                acc[mi][ni] = __builtin_amdgcn_mfma_f32_16x16x32_bf16(af[mi], bfr[ni], acc[mi][ni], 0, 0, 0);
    }

    // store feat1 as fp8 e4m3 (gather payload); C/D layout col=lane&15, row=quad*4+r
    #pragma unroll
    for (int mi = 0; mi < 4; ++mi) {
        #pragma unroll
        for (int ni = 0; ni < 4; ++ni) {
            int col = bn0 + wn + ni * 16 + lm;
            #pragma unroll
            for (int r = 0; r < 4; ++r) {
                int row = bm0 + wm + mi * 16 + quad * 4 + r;
                Cb8[(size_t)row * 256 + col] = f2fp8(acc[mi][ni][r]);
            }
        }
    }
    // fused elr1 (fp32 acc — unaffected by fp8 feat quantization)
    float alv[4], arv[4];
    #pragma unroll
    for (int ni = 0; ni < 4; ++ni) {
        int colg = bn0 + wn + ni * 16 + lm;
        alv[ni] = al1[colg];
        arv[ni] = ar1[colg];
    }
    int head0 = (bn0 + wn) >> 5;
    #pragma unroll
    for (int gg = 0; gg < 2; ++gg) {
        #pragma unroll
        for (int mi = 0; mi < 4; ++mi) {
            #pragma unroll
            for (int r = 0; r < 4; ++r) {
                float pel = acc[mi][2 * gg][r] * alv[2 * gg] + acc[mi][2 * gg + 1][r] * alv[2 * gg + 1];
                float per = acc[mi][2 * gg][r] * arv[2 * gg] + acc[mi][2 * gg + 1][r] * arv[2 * gg + 1];
                #pragma unroll
                for (int m = 1; m <= 8; m <<= 1) {
                    pel += __shfl_xor(pel, m, 64);
                    per += __shfl_xor(per, m, 64);
                }
                if (lm == 0) {
                    int row = bm0 + wm + mi * 16 + quad * 4 + r;
                    el1[row * 8 + head0 + gg] = pel;
                    er1[row * 8 + head0 + gg] = per;
                }
            }
        }
    }
}

// ---------------- L1 aggregation: one wave per dst node, fp8 feat gather ----------------

__global__ __launch_bounds__(256) void k_agg1(const unsigned char* __restrict__ feat8,
                                              const float* __restrict__ el1, const float* __restrict__ er1,
                                              const unsigned short* __restrict__ xb, const float* __restrict__ b1,
                                              const int* __restrict__ rowoff, const int* __restrict__ csr_src,
                                              unsigned short* __restrict__ y_b) {
    int v = (blockIdx.x * 256 + threadIdx.x) >> 6;
    int lane = threadIdx.x & 63;
    if (v >= M_PAD) return;
    int c0 = lane * 4;
    if (v >= N_NODES) {
        ushort4 z = {0, 0, 0, 0};
        *(ushort4*)(y_b + (size_t)v * 256 + c0) = z;
        return;
    }
    int h = lane >> 3;
    float er = er1[v * 8 + h];
    float ax = 0.f, ay = 0.f, az = 0.f, aw = 0.f, wsum = 0.f;
    int s = rowoff[v], e = rowoff[v + 1];
    int j = s;
    for (; j + 7 < e; j += 8) {
        int u[8];
        #pragma unroll
        for (int q = 0; q < 8; ++q) u[q] = csr_src[j + q];
        float tt[8];
        #pragma unroll
        for (int q = 0; q < 8; ++q) tt[q] = el1[u[q] * 8 + h] + er;
        uchar4 hv[8];
        #pragma unroll
        for (int q = 0; q < 8; ++q) hv[q] = *(const uchar4*)(feat8 + (size_t)u[q] * 256 + c0);
        #pragma unroll
        for (int q = 0; q < 8; ++q) {
            float tq = tt[q] > 0.f ? tt[q] : NEG_SLOPE * tt[q];
            float w = __expf(tq);
            wsum += w;
            ax += w * fp82f(hv[q].x);
            ay += w * fp82f(hv[q].y);
            az += w * fp82f(hv[q].z);
            aw += w * fp82f(hv[q].w);
        }
    }
    for (; j + 3 < e; j += 4) {
        int u[4];
        #pragma unroll
        for (int q = 0; q < 4; ++q) u[q] = csr_src[j + q];
        float tt[4];
        #pragma unroll
        for (int q = 0; q < 4; ++q) tt[q] = el1[u[q] * 8 + h] + er;
        uchar4 hv[4];
        #pragma unroll
        for (int q = 0; q < 4; ++q) hv[q] = *(const uchar4*)(feat8 + (size_t)u[q] * 256 + c0);
        #pragma unroll
        for (int q = 0; q < 4; ++q) {
            float tq = tt[q] > 0.f ? tt[q] : NEG_SLOPE * tt[q];
            float w = __expf(tq);
            wsum += w;
            ax += w * fp82f(hv[q].x);
            ay += w * fp82f(hv[q].y);
            az += w * fp82f(hv[q].z);
            aw += w * fp82f(hv[q].w);
        }
    }
    for (; j < e; ++j) {
        int u = csr_src[j];
        float t = el1[u * 8 + h] + er;
        uchar4 hh = *(const uchar4*)(feat8 + (size_t)u * 256 + c0);
        t = t > 0.f ? t : NEG_SLOPE * t;
        float w = __expf(t);
        wsum += w;
        ax += w * fp82f(hh.x);
        ay += w * fp82f(hh.y);
        az += w * fp82f(hh.z);
        aw += w * fp82f(hh.w);
    }
    float inv = (e > s) ? 1.f / wsum : 0.f;
    ushort4 rh = *(const ushort4*)(xb + (size_t)v * 256 + c0);
    float4 bb = *(const float4*)(b1 + c0);
    ushort4 o;
    o.x = f2bf(fmaxf(ax * inv + bf2f(rh.x) + bb.x, 0.f));
    o.y = f2bf(fmaxf(ay * inv + bf2f(rh.y) + bb.y, 0.f));
    o.z = f2bf(fmaxf(az * inv + bf2f(rh.z) + bb.z, 0.f));
    o.w = f2bf(fmaxf(aw * inv + bf2f(rh.w) + bb.w, 0.f));
    *(ushort4*)(y_b + (size_t)v * 256 + c0) = o;
}

// ---------------- GEMM2 + fused elr2: LDS-free, barrier-free, guard-free ----------------

__global__ __launch_bounds__(256) void k_gemm2f(const unsigned short* __restrict__ Ab,
                                                const unsigned short* __restrict__ BT,  // [64][256]
                                                const float* __restrict__ al2, const float* __restrict__ ar2,
                                                unsigned short* __restrict__ feat2b, float* __restrict__ res2,
                                                float* __restrict__ el2, float* __restrict__ er2) {
    const int t = threadIdx.x;
    const int bm0 = blockIdx.x * 128;
    const int wave = t >> 6, lane = t & 63;
    const int wm = (wave & 1) * 64, wn = (wave >> 1) * 32;
    const int lm = lane & 15, quad = lane >> 4;

    f32x4 acc[4][2];
    #pragma unroll
    for (int i = 0; i < 4; ++i)
        #pragma unroll
        for (int j = 0; j < 2; ++j)
            #pragma unroll
            for (int r = 0; r < 4; ++r) acc[i][j][r] = 0.f;

    const unsigned short* bp[2];
    const unsigned short* ap[4];
    #pragma unroll
    for (int i = 0; i < 2; ++i)
        bp[i] = BT + (size_t)(wn + i * 16 + lm) * 256 + quad * 8;
    #pragma unroll
    for (int i = 0; i < 4; ++i)
        ap[i] = Ab + (size_t)(bm0 + wm + i * 16 + lm) * 256 + quad * 8;

    #pragma unroll
    for (int k0 = 0; k0 < 256; k0 += 32) {
        bf16x8 af[4], bfr[2];
        #pragma unroll
        for (int i = 0; i < 2; ++i)
            bfr[i] = *(const bf16x8*)(bp[i] + k0);
        #pragma unroll
        for (int i = 0; i < 4; ++i)
            af[i] = *(const bf16x8*)(ap[i] + k0);
        #pragma unroll
        for (int mi = 0; mi < 4; ++mi)
            #pragma unroll
            for (int ni = 0; ni < 2; ++ni)
                acc[mi][ni] = __builtin_amdgcn_mfma_f32_16x16x32_bf16(af[mi], bfr[ni], acc[mi][ni], 0, 0, 0);
    }

    #pragma unroll
    for (int mi = 0; mi < 4; ++mi) {
        #pragma unroll
        for (int ni = 0; ni < 2; ++ni) {
            int col = wn + ni * 16 + lm;  // 0..63
            #pragma unroll
            for (int r = 0; r < 4; ++r) {
                int row = bm0 + wm + mi * 16 + quad * 4 + r;
                float val = acc[mi][ni][r];
                if (col < 32) feat2b[(size_t)row * 32 + col] = f2bf(val);
                else          res2[(size_t)row * 32 + col - 32] = val;
            }
        }
    }
    if (wn == 0) {
        float alv[2], arv[2];
        #pragma unroll
        for (int ni = 0; ni < 2; ++ni) {
            alv[ni] = al2[ni * 16 + lm];
            arv[ni] = ar2[ni * 16 + lm];
        }
        #pragma unroll
        for (int mi = 0; mi < 4; ++mi) {
            #pragma unroll
            for (int r = 0; r < 4; ++r) {
                float pel = acc[mi][0][r] * alv[0] + acc[mi][1][r] * alv[1];
                float per = acc[mi][0][r] * arv[0] + acc[mi][1][r] * arv[1];
                #pragma unroll
                for (int m = 1; m <= 8; m <<= 1) {
                    pel += __shfl_xor(pel, m, 64);
                    per += __shfl_xor(per, m, 64);
                }
                if (lm == 0) {
                    int row = bm0 + wm + mi * 16 + quad * 4 + r;
                    el2[row] = pel;
                    er2[row] = per;
                }
            }
        }
    }
}

// ---------------- L2 aggregation: 32 lanes per dst node (4-edge batched unroll) ----------------

__global__ __launch_bounds__(256) void k_agg2(const unsigned short* __restrict__ feat2b,
                                              const float* __restrict__ el2, const float* __restrict__ er2,
                                              const float* __restrict__ res2, const float* __restrict__ b2,
                                              const int* __restrict__ rowoff, const int* __restrict__ csr_src,
                                              float* __restrict__ out) {
    int g = blockIdx.x * 256 + threadIdx.x;
    int v = g >> 5;
    int c = g & 31;
    if (v >= N_NODES) return;
    float er = er2[v];
    float acc = 0.f, wsum = 0.f;
    int s = rowoff[v], e = rowoff[v + 1];
    int j = s;
    for (; j + 3 < e; j += 4) {
        int u[4];
        #pragma unroll
        for (int q = 0; q < 4; ++q) u[q] = csr_src[j + q];
        float tt[4];
        #pragma unroll
        for (int q = 0; q < 4; ++q) tt[q] = el2[u[q]] + er;
        unsigned short fv[4];
        #pragma unroll
        for (int q = 0; q < 4; ++q) fv[q] = feat2b[(size_t)u[q] * 32 + c];
        #pragma unroll
        for (int q = 0; q < 4; ++q) {
            float tq = tt[q] > 0.f ? tt[q] : NEG_SLOPE * tt[q];
            float w = __expf(tq);
            wsum += w;
            acc += w * bf2f(fv[q]);
        }
    }
    for (; j < e; ++j) {
        int u = csr_src[j];
        float t = el2[u] + er;
        t = t > 0.f ? t : NEG_SLOPE * t;
        float w = __expf(t);
        wsum += w;
        acc += w * bf2f(feat2b[(size_t)u * 32 + c]);
    }
    float inv = (e > s) ? 1.f / wsum : 0.f;
    out[(size_t)v * 32 + c] = acc * inv + res2[(size_t)v * 32 + c] + b2[c];
}

// ---------------- launch ----------------

extern "C" void kernel_launch(void* const* d_in, const int* in_sizes, int n_in,
                              void* d_out, int out_size, void* d_ws, size_t ws_size,
                              hipStream_t stream) {
    const float* x     = (const float*)d_in[0];
    const int*   src   = (const int*)d_in[1];
    const int*   dst   = (const int*)d_in[2];
    const float* W1    = (const float*)d_in[3];
    const float* al1   = (const float*)d_in[4];
    const float* ar1   = (const float*)d_in[5];
    const float* b1    = (const float*)d_in[6];
    const float* W2    = (const float*)d_in[7];
    const float* al2   = (const float*)d_in[8];
    const float* ar2   = (const float*)d_in[9];
    const float* resW2 = (const float*)d_in[10];
    const float* b2    = (const float*)d_in[11];
    float* out = (float*)d_out;

    char* ws = (char*)d_ws;
    size_t off = 0;
    auto alloc = [&](size_t bytes) {
        void* p = ws + off;
        off += (bytes + 255) & ~(size_t)255;
        return p;
    };
    unsigned short* xb     = (unsigned short*)alloc((size_t)M_PAD * 256 * 2);
    unsigned char*  feat8  = (unsigned char*)alloc((size_t)M_PAD * 256);
    unsigned short* y_b    = (unsigned short*)alloc((size_t)M_PAD * 256 * 2);
    unsigned short* W1T    = (unsigned short*)alloc((size_t)256 * 256 * 2);
    unsigned short* W2T    = (unsigned short*)alloc((size_t)64 * 256 * 2);
    unsigned short* feat2b = (unsigned short*)alloc((size_t)M_PAD * 32 * 2);
    float* res2   = (float*)alloc((size_t)M_PAD * 32 * 4);
    float* el1    = (float*)alloc((size_t)M_PAD * 8 * 4);
    float* er1    = (float*)alloc((size_t)M_PAD * 8 * 4);
    float* el2    = (float*)alloc((size_t)M_PAD * 4);
    float* er2    = (float*)alloc((size_t)M_PAD * 4);
    int*   deg    = (int*)alloc((size_t)N_NODES * 4);
    int*   rowoff = (int*)alloc((size_t)(N_NODES + 1) * 4);
    int*   wp     = (int*)alloc((size_t)N_NODES * 4);
    int*   bsum   = (int*)alloc((size_t)SCAN_NB * 4);
    int*   csr    = (int*)alloc((size_t)N_EDGES * 4);
    (void)ws_size;

    // weights transpose + deg zeroing
    k_trans<<<dim3(10, 8), 256, 0, stream>>>(W1, W2, resW2, W1T, W2T, deg);

    // CSR hist + xb cast
    k_hist<<<(N_EDGES + 255) / 256, 256, 0, stream>>>(dst, deg, x, xb);

    // GEMM1 (fp8 out) + co-scheduled scan1
    k_gemm1s<<<GEMM1_BLOCKS + SCAN_NB, 256, 0, stream>>>(xb, W1T, al1, ar1, feat8, el1, er1,
                                                         deg, rowoff, bsum);
    k_scan3<<<SCAN_NB, SCAN_BLK, 0, stream>>>(deg, rowoff, wp, bsum);
    k_scatter<<<(N_EDGES + 255) / 256, 256, 0, stream>>>(src, dst, wp, csr);

    // Layer 1 aggregation (fp8 gather)
    k_agg1<<<(M_PAD * 64) / 256, 256, 0, stream>>>(feat8, el1, er1, xb, b1, rowoff, csr, y_b);

    // Layer 2
    k_gemm2f<<<M_PAD / 128, 256, 0, stream>>>(y_b, W2T, al2, ar2, feat2b, res2, el2, er2);
    k_agg2<<<(N_NODES * 32) / 256, 256, 0, stream>>>(feat2b, el2, er2, res2, b2, rowoff, csr, out);
}